// Round 1
// baseline (1893.518 us; speedup 1.0000x reference)
//
#include <hip/hip_runtime.h>
#include <hip/hip_bf16.h>

typedef __attribute__((ext_vector_type(8))) short bf16x8;
typedef __attribute__((ext_vector_type(4))) float f32x4;
typedef __attribute__((ext_vector_type(4))) unsigned short u16x4;

#define DEVINL static __device__ __forceinline__

constexpr int BMx = 128, BNx = 128, BKx = 64;
constexpr int NTILES = 8;   // N = 1024 fixed for every GEMM in this pipeline
constexpr int KD = 1024;    // K = 1024 fixed

DEVINL unsigned short f2bf(float f) {
  union { float f; unsigned u; } a; a.f = f;
  return (unsigned short)((a.u + 0x7fffu + ((a.u >> 16) & 1u)) >> 16);  // RNE
}

typedef __attribute__((address_space(1))) const unsigned char ga_u8;
typedef __attribute__((address_space(3))) unsigned char ls_u8;

// C[M][1024] = A[M][1024] * B[1024][1024]^T   (both operands K-major, "B^T" layout)
// MODE 0: A,B f32 (converted to bf16 during reg-staging), +bias, C bf16
// MODE 1: A,B bf16 (global_load_lds staging), C f32 with LeakyReLU(0.1),
//         plus rnorm2[col] += sum_rows leaky^2 (atomic)
// MODE 2: A,B bf16, C f32 plain
template<int MODE>
__global__ __launch_bounds__(256, 2) void gemm_bt(
    const void* __restrict__ Av, const void* __restrict__ Bv,
    const float* __restrict__ bias, void* __restrict__ Cv,
    float* __restrict__ rnorm2, int mtiles,
    long long sAz, long long sBz, long long sCz, long long sRz)
{
  (void)mtiles;
  alignas(16) __shared__ char lds[(BMx + BNx) * BKx * 2];  // 32 KiB
  char* ldsA = lds;
  char* ldsB = lds + BMx * BKx * 2;

  const int tid = threadIdx.x;
  const int lane = tid & 63;
  const int wv = tid >> 6;
  const int wm = wv >> 1, wn = wv & 1;
  const int kg = lane >> 4;
  const int ml = lane & 15;
  const int z = blockIdx.y;
  const int mt = (int)blockIdx.x / NTILES;
  const int nt = (int)blockIdx.x % NTILES;
  const int m0 = mt * BMx, n0 = nt * BNx;

  f32x4 acc[4][4];
  const f32x4 zero4 = {0.f, 0.f, 0.f, 0.f};
#pragma unroll
  for (int i = 0; i < 4; ++i)
#pragma unroll
    for (int j = 0; j < 4; ++j) acc[i][j] = zero4;

  const float* Af32 = (const float*)Av;
  const float* Bf32 = (const float*)Bv;
  const unsigned short* Abf = (const unsigned short*)Av + (size_t)z * (size_t)sAz;
  const unsigned short* Bbf = (const unsigned short*)Bv + (size_t)z * (size_t)sBz;

  for (int kt = 0; kt < KD / BKx; ++kt) {
    const int k0 = kt * BKx;
    if (MODE == 0) {
      // reg-staged f32 -> bf16 conversion, swizzled ds_write_b128
#pragma unroll
      for (int i = 0; i < 4; ++i) {
        int slot = i * 256 + tid;
        int r = slot >> 3, c = slot & 7;
        int gc = c ^ (r & 7);
        {
          const float* gp = Af32 + (size_t)(m0 + r) * KD + k0 + gc * 8;
          f32x4 x = *(const f32x4*)gp;
          f32x4 y = *(const f32x4*)(gp + 4);
          union { unsigned short s[8]; bf16x8 v; } u;
          u.s[0]=f2bf(x[0]); u.s[1]=f2bf(x[1]); u.s[2]=f2bf(x[2]); u.s[3]=f2bf(x[3]);
          u.s[4]=f2bf(y[0]); u.s[5]=f2bf(y[1]); u.s[6]=f2bf(y[2]); u.s[7]=f2bf(y[3]);
          *(bf16x8*)(ldsA + slot * 16) = u.v;
        }
        {
          const float* gp = Bf32 + (size_t)(n0 + r) * KD + k0 + gc * 8;
          f32x4 x = *(const f32x4*)gp;
          f32x4 y = *(const f32x4*)(gp + 4);
          union { unsigned short s[8]; bf16x8 v; } u;
          u.s[0]=f2bf(x[0]); u.s[1]=f2bf(x[1]); u.s[2]=f2bf(x[2]); u.s[3]=f2bf(x[3]);
          u.s[4]=f2bf(y[0]); u.s[5]=f2bf(y[1]); u.s[6]=f2bf(y[2]); u.s[7]=f2bf(y[3]);
          *(bf16x8*)(ldsB + slot * 16) = u.v;
        }
      }
    } else {
      // async global->LDS, width 16; LDS dest wave-uniform base + lane*16,
      // swizzle applied by permuting the GLOBAL source chunk (rule #21)
#pragma unroll
      for (int i = 0; i < 4; ++i) {
        int slot = i * 256 + tid;
        int r = slot >> 3, c = slot & 7;
        int gc = c ^ (r & 7);
        const unsigned short* gpa = Abf + (size_t)(m0 + r) * KD + k0 + gc * 8;
        const unsigned short* gpb = Bbf + (size_t)(n0 + r) * KD + k0 + gc * 8;
        char* la = ldsA + (size_t)(i * 256 + wv * 64) * 16;
        char* lb = ldsB + (size_t)(i * 256 + wv * 64) * 16;
        __builtin_amdgcn_global_load_lds((ga_u8*)gpa, (ls_u8*)la, 16, 0, 0);
        __builtin_amdgcn_global_load_lds((ga_u8*)gpb, (ls_u8*)lb, 16, 0, 0);
      }
    }
    __syncthreads();

#pragma unroll
    for (int kk = 0; kk < BKx; kk += 32) {
      const int kb = kk * 2 + kg * 16;
      bf16x8 af[4], bfr[4];
#pragma unroll
      for (int mi = 0; mi < 4; ++mi) {
        int row = wm * 64 + mi * 16 + ml;
        af[mi] = *(const bf16x8*)(ldsA + row * (BKx * 2) + (kb ^ ((row & 7) << 4)));
      }
#pragma unroll
      for (int ni = 0; ni < 4; ++ni) {
        int row = wn * 64 + ni * 16 + ml;
        bfr[ni] = *(const bf16x8*)(ldsB + row * (BKx * 2) + (kb ^ ((row & 7) << 4)));
      }
#pragma unroll
      for (int mi = 0; mi < 4; ++mi)
#pragma unroll
        for (int ni = 0; ni < 4; ++ni)
          acc[mi][ni] = __builtin_amdgcn_mfma_f32_16x16x32_bf16(af[mi], bfr[ni], acc[mi][ni], 0, 0, 0);
    }
    __syncthreads();
  }

  // Epilogue. C/D layout: col = lane&15, row = (lane>>4)*4 + j  [m89-verified]
  if (MODE == 0) {
    unsigned short* C = (unsigned short*)Cv;
#pragma unroll
    for (int ni = 0; ni < 4; ++ni) {
      int col = n0 + wn * 64 + ni * 16 + ml;
      float bv = bias[col];
#pragma unroll
      for (int mi = 0; mi < 4; ++mi) {
        int rb = m0 + wm * 64 + mi * 16 + kg * 4;
#pragma unroll
        for (int j = 0; j < 4; ++j)
          C[(size_t)(rb + j) * 1024 + col] = f2bf(acc[mi][ni][j] + bv);
      }
    }
  } else if (MODE == 1) {
    float* C = (float*)Cv + (size_t)z * (size_t)sCz;
    float* rn = rnorm2 + (size_t)z * (size_t)sRz;
#pragma unroll
    for (int ni = 0; ni < 4; ++ni) {
      int col = n0 + wn * 64 + ni * 16 + ml;
      float cs = 0.f;
#pragma unroll
      for (int mi = 0; mi < 4; ++mi) {
        int rb = m0 + wm * 64 + mi * 16 + kg * 4;
#pragma unroll
        for (int j = 0; j < 4; ++j) {
          float v = acc[mi][ni][j];
          v = v >= 0.f ? v : 0.1f * v;   // LeakyReLU(0.1)
          C[(size_t)(rb + j) * 1024 + col] = v;
          cs += v * v;
        }
      }
      cs += __shfl_xor(cs, 16);
      cs += __shfl_xor(cs, 32);
      if (kg == 0) atomicAdd(&rn[col], cs);
    }
  } else {
    float* C = (float*)Cv + (size_t)z * (size_t)sCz;
#pragma unroll
    for (int ni = 0; ni < 4; ++ni) {
      int col = n0 + wn * 64 + ni * 16 + ml;
#pragma unroll
      for (int mi = 0; mi < 4; ++mi) {
        int rb = m0 + wm * 64 + mi * 16 + kg * 4;
#pragma unroll
        for (int j = 0; j < 4; ++j)
          C[(size_t)(rb + j) * 1024 + col] = acc[mi][ni][j];
      }
    }
  }
}

// ctxT[b][d][s] (bf16) = ctx[b][s][d] (f32)
__global__ __launch_bounds__(256) void transpose_ctx_k(
    const float* __restrict__ src, unsigned short* __restrict__ dst)
{
  __shared__ float tile[32][33];
  int tx = threadIdx.x & 31, ty = threadIdx.x >> 5;   // 32 x 8
  int s0 = blockIdx.x * 32, d0 = blockIdx.y * 32;
  const float* S = src + (size_t)blockIdx.z * 1024 * 1024;
  unsigned short* D = dst + (size_t)blockIdx.z * 1024 * 1024;
#pragma unroll
  for (int i = 0; i < 4; ++i)
    tile[ty + i * 8][tx] = S[(size_t)(s0 + ty + i * 8) * 1024 + d0 + tx];
  __syncthreads();
#pragma unroll
  for (int i = 0; i < 4; ++i) {
    int d = ty + i * 8;
    D[(size_t)(d0 + d) * 1024 + s0 + tx] = f2bf(tile[tx][d]);
  }
}

// one block per (batch-in-chunk, q): logits = smooth * S[q][s] / (sqrt(rnorm2[s])+1e-8)
// softmax over s=0..1023, output P bf16
__global__ __launch_bounds__(256) void softmax_k(
    const float* __restrict__ S, const float* __restrict__ rnorm2,
    const float* __restrict__ smoothp, unsigned short* __restrict__ P)
{
  __shared__ float shm[4], shs[4];
  const int t = threadIdx.x;
  const int z = blockIdx.x >> 9;            // QL = 512
  const float sm = *smoothp;
  f32x4 s4 = ((const f32x4*)(S + (size_t)blockIdx.x * 1024))[t];
  f32x4 r4 = ((const f32x4*)(rnorm2 + (size_t)z * 1024))[t];
  f32x4 lg;
  lg[0] = sm * s4[0] / (sqrtf(r4[0]) + 1e-8f);
  lg[1] = sm * s4[1] / (sqrtf(r4[1]) + 1e-8f);
  lg[2] = sm * s4[2] / (sqrtf(r4[2]) + 1e-8f);
  lg[3] = sm * s4[3] / (sqrtf(r4[3]) + 1e-8f);
  float mx = fmaxf(fmaxf(lg[0], lg[1]), fmaxf(lg[2], lg[3]));
#pragma unroll
  for (int o = 32; o; o >>= 1) mx = fmaxf(mx, __shfl_xor(mx, o));
  if ((t & 63) == 0) shm[t >> 6] = mx;
  __syncthreads();
  mx = fmaxf(fmaxf(shm[0], shm[1]), fmaxf(shm[2], shm[3]));
  f32x4 e;
  e[0] = __expf(lg[0] - mx); e[1] = __expf(lg[1] - mx);
  e[2] = __expf(lg[2] - mx); e[3] = __expf(lg[3] - mx);
  float sum = e[0] + e[1] + e[2] + e[3];
#pragma unroll
  for (int o = 32; o; o >>= 1) sum += __shfl_xor(sum, o);
  if ((t & 63) == 0) shs[t >> 6] = sum;
  __syncthreads();
  sum = shs[0] + shs[1] + shs[2] + shs[3];
  float inv = 1.f / sum;
  u16x4 p;
  p[0] = f2bf(e[0] * inv); p[1] = f2bf(e[1] * inv);
  p[2] = f2bf(e[2] * inv); p[3] = f2bf(e[3] * inv);
  ((u16x4*)(P + (size_t)blockIdx.x * 1024))[t] = p;
}

// one block per row of 1024: out = w / (sqrt(sum w^2) + 1e-8)
__global__ __launch_bounds__(256) void l2norm_k(
    const float* __restrict__ W, float* __restrict__ O)
{
  __shared__ float shs[4];
  const int t = threadIdx.x;
  f32x4 v = ((const f32x4*)(W + (size_t)blockIdx.x * 1024))[t];
  float ss = v[0]*v[0] + v[1]*v[1] + v[2]*v[2] + v[3]*v[3];
#pragma unroll
  for (int o = 32; o; o >>= 1) ss += __shfl_xor(ss, o);
  if ((t & 63) == 0) shs[t >> 6] = ss;
  __syncthreads();
  ss = shs[0] + shs[1] + shs[2] + shs[3];
  float inv = 1.f / (sqrtf(ss) + 1e-8f);
  f32x4 o4 = { v[0]*inv, v[1]*inv, v[2]*inv, v[3]*inv };
  ((f32x4*)(O + (size_t)blockIdx.x * 1024))[t] = o4;
}

extern "C" void kernel_launch(void* const* d_in, const int* in_sizes, int n_in,
                              void* d_out, int out_size, void* d_ws, size_t ws_size,
                              hipStream_t stream)
{
  (void)in_sizes; (void)n_in; (void)out_size;
  const float* query   = (const float*)d_in[0];  // [128][512][1024]
  const float* context = (const float*)d_in[1];  // [128][1024][1024]
  const float* Wq = (const float*)d_in[2];
  const float* bq = (const float*)d_in[3];
  const float* Wk = (const float*)d_in[4];
  const float* bk = (const float*)d_in[5];
  const float* smooth = (const float*)d_in[6];
  float* out = (float*)d_out;

  const int B = 128, QL = 512, SL = 1024, D = 1024;

  // per-batch scratch: simq/P (bf16) + simk (bf16) + ctxT (bf16) + S/wc (f32) + rnorm2
  const size_t perB =
      (size_t)QL * D * 2 + (size_t)SL * D * 2 + (size_t)D * SL * 2 +
      (size_t)QL * SL * 4 + (size_t)SL * 4 + 2048;
  size_t usable = ws_size > 8192 ? ws_size - 8192 : 0;
  int C = (int)(usable / perB);
  if (C > B) C = B;
  if (C < 1) C = 1;

  char* p = (char*)d_ws;
  auto alloc = [&](size_t bytes) {
    char* r = p; p += (bytes + 255) & ~(size_t)255; return r;
  };
  unsigned short* simq = (unsigned short*)alloc((size_t)C * QL * D * 2);  // later P
  unsigned short* simk = (unsigned short*)alloc((size_t)C * SL * D * 2);
  unsigned short* ctxT = (unsigned short*)alloc((size_t)C * D * SL * 2);
  float* Sbuf = (float*)alloc((size_t)C * QL * SL * 4);                   // later wc
  float* rn   = (float*)alloc((size_t)C * SL * 4);

  for (int b0 = 0; b0 < B; b0 += C) {
    const int Cc = (B - b0) < C ? (B - b0) : C;
    hipMemsetAsync(rn, 0, (size_t)Cc * SL * 4, stream);
    // projections: sim_q = query Wq^T + bq ; sim_k = ctx Wk^T + bk  (bf16 out)
    gemm_bt<0><<<dim3(Cc * 4 * NTILES, 1), 256, 0, stream>>>(
        query + (size_t)b0 * QL * D, Wq, bq, simq, nullptr, Cc * 4, 0, 0, 0, 0);
    gemm_bt<0><<<dim3(Cc * 8 * NTILES, 1), 256, 0, stream>>>(
        context + (size_t)b0 * SL * D, Wk, bk, simk, nullptr, Cc * 8, 0, 0, 0, 0);
    transpose_ctx_k<<<dim3(32, 32, Cc), 256, 0, stream>>>(
        context + (size_t)b0 * SL * D, ctxT);
    // S^T[q][s] = leaky(simq . simk), rnorm2[s] += sum_q leaky^2
    gemm_bt<1><<<dim3(4 * NTILES, Cc), 256, 0, stream>>>(
        simq, simk, nullptr, Sbuf, rn, 4,
        (long long)QL * D, (long long)SL * D, (long long)QL * SL, (long long)SL);
    softmax_k<<<Cc * QL, 256, 0, stream>>>(Sbuf, rn, smooth, simq /* P */);
    // wc = P @ ctxT^T  (contraction over s)
    gemm_bt<2><<<dim3(4 * NTILES, Cc), 256, 0, stream>>>(
        simq /* P */, ctxT, nullptr, Sbuf /* wc */, nullptr, 4,
        (long long)QL * SL, (long long)D * SL, (long long)QL * D, 0);
    l2norm_k<<<Cc * QL, 256, 0, stream>>>(Sbuf, out + (size_t)b0 * QL * D);
  }
}

// Round 2
// 1676.849 us; speedup vs baseline: 1.1292x; 1.1292x over previous
//
#include <hip/hip_runtime.h>
#include <hip/hip_bf16.h>

typedef __attribute__((ext_vector_type(8))) short bf16x8;
typedef __attribute__((ext_vector_type(4))) float f32x4;
typedef __attribute__((ext_vector_type(4))) unsigned short u16x4;

#define DEVINL static __device__ __forceinline__

constexpr int BMx = 128, BNx = 128, BKx = 64;
constexpr int NTILES = 8;   // N = 1024 fixed for every GEMM in this pipeline
constexpr int KD = 1024;    // K = 1024 fixed

DEVINL unsigned short f2bf(float f) {
  union { float f; unsigned u; } a; a.f = f;
  return (unsigned short)((a.u + 0x7fffu + ((a.u >> 16) & 1u)) >> 16);  // RNE
}

typedef __attribute__((address_space(1))) const unsigned char ga_u8;
typedef __attribute__((address_space(3))) unsigned char ls_u8;

// C[M][1024] = A[M][1024] * B[1024][1024]^T   (both operands K-major, "B^T" layout)
// Grid is 1D, XCD-chunk swizzled; work order: z-major, then mt, nt innermost
// (consecutive work items share the A panel; one batch stays on one XCD's L2).
// MODE 0: A,B f32 (converted to bf16 during reg-staging), +bias, C bf16
// MODE 1: A,B bf16 (global_load_lds staging), C f32 with LeakyReLU(0.1),
//         plus rnorm2[col] += sum_rows leaky^2 (atomic)
// MODE 2: A,B bf16, C f32 plain
template<int MODE>
__global__ __launch_bounds__(256, 4) void gemm_bt(
    const void* __restrict__ Av, const void* __restrict__ Bv,
    const float* __restrict__ bias, void* __restrict__ Cv,
    float* __restrict__ rnorm2, int mt_per_z,
    long long sAz, long long sBz, long long sCz, long long sRz)
{
  alignas(16) __shared__ char lds[(BMx + BNx) * BKx * 2];  // 32 KiB
  char* ldsA = lds;
  char* ldsB = lds + BMx * BKx * 2;

  const int tid = threadIdx.x;
  const int lane = tid & 63;
  const int wv = tid >> 6;
  const int wm = wv >> 1, wn = wv & 1;
  const int kg = lane >> 4;
  const int ml = lane & 15;

  // XCD-chunked bijective swizzle (nwg is always a multiple of 8 here):
  // block bid runs on XCD bid%8 and takes work item from that XCD's
  // contiguous chunk -> per-batch operand panels stay in one XCD's L2.
  const int nwg = (int)gridDim.x;
  const int bid = (int)blockIdx.x;
  const int w = (bid & 7) * (nwg >> 3) + (bid >> 3);
  const int z = w / (mt_per_z * NTILES);
  const int rem = w - z * mt_per_z * NTILES;
  const int mt = rem >> 3;
  const int nt = rem & 7;
  const int m0 = mt * BMx, n0 = nt * BNx;

  f32x4 acc[4][4];
  const f32x4 zero4 = {0.f, 0.f, 0.f, 0.f};
#pragma unroll
  for (int i = 0; i < 4; ++i)
#pragma unroll
    for (int j = 0; j < 4; ++j) acc[i][j] = zero4;

  const float* Af32 = (const float*)Av;
  const float* Bf32 = (const float*)Bv;
  const unsigned short* Abf = (const unsigned short*)Av + (size_t)z * (size_t)sAz;
  const unsigned short* Bbf = (const unsigned short*)Bv + (size_t)z * (size_t)sBz;

  for (int kt = 0; kt < KD / BKx; ++kt) {
    const int k0 = kt * BKx;
    if (MODE == 0) {
      // reg-staged f32 -> bf16 conversion, swizzled ds_write_b128
#pragma unroll
      for (int i = 0; i < 4; ++i) {
        int slot = i * 256 + tid;
        int r = slot >> 3, c = slot & 7;
        int gc = c ^ (r & 7);
        {
          const float* gp = Af32 + (size_t)(m0 + r) * KD + k0 + gc * 8;
          f32x4 x = *(const f32x4*)gp;
          f32x4 y = *(const f32x4*)(gp + 4);
          union { unsigned short s[8]; bf16x8 v; } u;
          u.s[0]=f2bf(x[0]); u.s[1]=f2bf(x[1]); u.s[2]=f2bf(x[2]); u.s[3]=f2bf(x[3]);
          u.s[4]=f2bf(y[0]); u.s[5]=f2bf(y[1]); u.s[6]=f2bf(y[2]); u.s[7]=f2bf(y[3]);
          *(bf16x8*)(ldsA + slot * 16) = u.v;
        }
        {
          const float* gp = Bf32 + (size_t)(n0 + r) * KD + k0 + gc * 8;
          f32x4 x = *(const f32x4*)gp;
          f32x4 y = *(const f32x4*)(gp + 4);
          union { unsigned short s[8]; bf16x8 v; } u;
          u.s[0]=f2bf(x[0]); u.s[1]=f2bf(x[1]); u.s[2]=f2bf(x[2]); u.s[3]=f2bf(x[3]);
          u.s[4]=f2bf(y[0]); u.s[5]=f2bf(y[1]); u.s[6]=f2bf(y[2]); u.s[7]=f2bf(y[3]);
          *(bf16x8*)(ldsB + slot * 16) = u.v;
        }
      }
    } else {
      // async global->LDS, width 16; LDS dest wave-uniform base + lane*16,
      // swizzle applied by permuting the GLOBAL source chunk (rule #21)
#pragma unroll
      for (int i = 0; i < 4; ++i) {
        int slot = i * 256 + tid;
        int r = slot >> 3, c = slot & 7;
        int gc = c ^ (r & 7);
        const unsigned short* gpa = Abf + (size_t)(m0 + r) * KD + k0 + gc * 8;
        const unsigned short* gpb = Bbf + (size_t)(n0 + r) * KD + k0 + gc * 8;
        char* la = ldsA + (size_t)(i * 256 + wv * 64) * 16;
        char* lb = ldsB + (size_t)(i * 256 + wv * 64) * 16;
        __builtin_amdgcn_global_load_lds((ga_u8*)gpa, (ls_u8*)la, 16, 0, 0);
        __builtin_amdgcn_global_load_lds((ga_u8*)gpb, (ls_u8*)lb, 16, 0, 0);
      }
    }
    __syncthreads();

#pragma unroll
    for (int kk = 0; kk < BKx; kk += 32) {
      const int kb = kk * 2 + kg * 16;
      bf16x8 af[4], bfr[4];
#pragma unroll
      for (int mi = 0; mi < 4; ++mi) {
        int row = wm * 64 + mi * 16 + ml;
        af[mi] = *(const bf16x8*)(ldsA + row * (BKx * 2) + (kb ^ ((row & 7) << 4)));
      }
#pragma unroll
      for (int ni = 0; ni < 4; ++ni) {
        int row = wn * 64 + ni * 16 + ml;
        bfr[ni] = *(const bf16x8*)(ldsB + row * (BKx * 2) + (kb ^ ((row & 7) << 4)));
      }
#pragma unroll
      for (int mi = 0; mi < 4; ++mi)
#pragma unroll
        for (int ni = 0; ni < 4; ++ni)
          acc[mi][ni] = __builtin_amdgcn_mfma_f32_16x16x32_bf16(af[mi], bfr[ni], acc[mi][ni], 0, 0, 0);
    }
    __syncthreads();
  }

  // Epilogue. C/D layout: col = lane&15, row = (lane>>4)*4 + j  [m89-verified]
  if (MODE == 0) {
    unsigned short* C = (unsigned short*)Cv;
#pragma unroll
    for (int ni = 0; ni < 4; ++ni) {
      int col = n0 + wn * 64 + ni * 16 + ml;
      float bv = bias[col];
#pragma unroll
      for (int mi = 0; mi < 4; ++mi) {
        int rb = m0 + wm * 64 + mi * 16 + kg * 4;
#pragma unroll
        for (int j = 0; j < 4; ++j)
          C[(size_t)(rb + j) * 1024 + col] = f2bf(acc[mi][ni][j] + bv);
      }
    }
  } else if (MODE == 1) {
    float* C = (float*)Cv + (size_t)z * (size_t)sCz;
    float* rn = rnorm2 + (size_t)z * (size_t)sRz;
#pragma unroll
    for (int ni = 0; ni < 4; ++ni) {
      int col = n0 + wn * 64 + ni * 16 + ml;
      float cs = 0.f;
#pragma unroll
      for (int mi = 0; mi < 4; ++mi) {
        int rb = m0 + wm * 64 + mi * 16 + kg * 4;
#pragma unroll
        for (int j = 0; j < 4; ++j) {
          float v = acc[mi][ni][j];
          v = v >= 0.f ? v : 0.1f * v;   // LeakyReLU(0.1)
          C[(size_t)(rb + j) * 1024 + col] = v;
          cs += v * v;
        }
      }
      cs += __shfl_xor(cs, 16);
      cs += __shfl_xor(cs, 32);
      if (kg == 0) atomicAdd(&rn[col], cs);
    }
  } else {
    float* C = (float*)Cv + (size_t)z * (size_t)sCz;
#pragma unroll
    for (int ni = 0; ni < 4; ++ni) {
      int col = n0 + wn * 64 + ni * 16 + ml;
#pragma unroll
      for (int mi = 0; mi < 4; ++mi) {
        int rb = m0 + wm * 64 + mi * 16 + kg * 4;
#pragma unroll
        for (int j = 0; j < 4; ++j)
          C[(size_t)(rb + j) * 1024 + col] = acc[mi][ni][j];
      }
    }
  }
}

// ctxT[b][d][s] (bf16) = ctx[b][s][d] (f32)
__global__ __launch_bounds__(256) void transpose_ctx_k(
    const float* __restrict__ src, unsigned short* __restrict__ dst)
{
  __shared__ float tile[32][33];
  int tx = threadIdx.x & 31, ty = threadIdx.x >> 5;   // 32 x 8
  int s0 = blockIdx.x * 32, d0 = blockIdx.y * 32;
  const float* S = src + (size_t)blockIdx.z * 1024 * 1024;
  unsigned short* D = dst + (size_t)blockIdx.z * 1024 * 1024;
#pragma unroll
  for (int i = 0; i < 4; ++i)
    tile[ty + i * 8][tx] = S[(size_t)(s0 + ty + i * 8) * 1024 + d0 + tx];
  __syncthreads();
#pragma unroll
  for (int i = 0; i < 4; ++i) {
    int d = ty + i * 8;
    D[(size_t)(d0 + d) * 1024 + s0 + tx] = f2bf(tile[tx][d]);
  }
}

// one block per (batch-in-chunk, q): logits = smooth * S[q][s] / (sqrt(rnorm2[s])+1e-8)
// softmax over s=0..1023, output P bf16
__global__ __launch_bounds__(256) void softmax_k(
    const float* __restrict__ S, const float* __restrict__ rnorm2,
    const float* __restrict__ smoothp, unsigned short* __restrict__ P)
{
  __shared__ float shm[4], shs[4];
  const int t = threadIdx.x;
  const int z = blockIdx.x >> 9;            // QL = 512
  const float sm = *smoothp;
  f32x4 s4 = ((const f32x4*)(S + (size_t)blockIdx.x * 1024))[t];
  f32x4 r4 = ((const f32x4*)(rnorm2 + (size_t)z * 1024))[t];
  f32x4 lg;
  lg[0] = sm * s4[0] / (sqrtf(r4[0]) + 1e-8f);
  lg[1] = sm * s4[1] / (sqrtf(r4[1]) + 1e-8f);
  lg[2] = sm * s4[2] / (sqrtf(r4[2]) + 1e-8f);
  lg[3] = sm * s4[3] / (sqrtf(r4[3]) + 1e-8f);
  float mx = fmaxf(fmaxf(lg[0], lg[1]), fmaxf(lg[2], lg[3]));
#pragma unroll
  for (int o = 32; o; o >>= 1) mx = fmaxf(mx, __shfl_xor(mx, o));
  if ((t & 63) == 0) shm[t >> 6] = mx;
  __syncthreads();
  mx = fmaxf(fmaxf(shm[0], shm[1]), fmaxf(shm[2], shm[3]));
  f32x4 e;
  e[0] = __expf(lg[0] - mx); e[1] = __expf(lg[1] - mx);
  e[2] = __expf(lg[2] - mx); e[3] = __expf(lg[3] - mx);
  float sum = e[0] + e[1] + e[2] + e[3];
#pragma unroll
  for (int o = 32; o; o >>= 1) sum += __shfl_xor(sum, o);
  if ((t & 63) == 0) shs[t >> 6] = sum;
  __syncthreads();
  sum = shs[0] + shs[1] + shs[2] + shs[3];
  float inv = 1.f / sum;
  u16x4 p;
  p[0] = f2bf(e[0] * inv); p[1] = f2bf(e[1] * inv);
  p[2] = f2bf(e[2] * inv); p[3] = f2bf(e[3] * inv);
  ((u16x4*)(P + (size_t)blockIdx.x * 1024))[t] = p;
}

// one block per row of 1024: out = w / (sqrt(sum w^2) + 1e-8)
__global__ __launch_bounds__(256) void l2norm_k(
    const float* __restrict__ W, float* __restrict__ O)
{
  __shared__ float shs[4];
  const int t = threadIdx.x;
  f32x4 v = ((const f32x4*)(W + (size_t)blockIdx.x * 1024))[t];
  float ss = v[0]*v[0] + v[1]*v[1] + v[2]*v[2] + v[3]*v[3];
#pragma unroll
  for (int o = 32; o; o >>= 1) ss += __shfl_xor(ss, o);
  if ((t & 63) == 0) shs[t >> 6] = ss;
  __syncthreads();
  ss = shs[0] + shs[1] + shs[2] + shs[3];
  float inv = 1.f / (sqrtf(ss) + 1e-8f);
  f32x4 o4 = { v[0]*inv, v[1]*inv, v[2]*inv, v[3]*inv };
  ((f32x4*)(O + (size_t)blockIdx.x * 1024))[t] = o4;
}

extern "C" void kernel_launch(void* const* d_in, const int* in_sizes, int n_in,
                              void* d_out, int out_size, void* d_ws, size_t ws_size,
                              hipStream_t stream)
{
  (void)in_sizes; (void)n_in; (void)out_size;
  const float* query   = (const float*)d_in[0];  // [128][512][1024]
  const float* context = (const float*)d_in[1];  // [128][1024][1024]
  const float* Wq = (const float*)d_in[2];
  const float* bq = (const float*)d_in[3];
  const float* Wk = (const float*)d_in[4];
  const float* bk = (const float*)d_in[5];
  const float* smooth = (const float*)d_in[6];
  float* out = (float*)d_out;

  const int B = 128, QL = 512, SL = 1024, D = 1024;

  // per-batch scratch: simq/P (bf16) + simk (bf16) + ctxT (bf16) + S/wc (f32) + rnorm2
  const size_t perB =
      (size_t)QL * D * 2 + (size_t)SL * D * 2 + (size_t)D * SL * 2 +
      (size_t)QL * SL * 4 + (size_t)SL * 4 + 2048;
  size_t usable = ws_size > 8192 ? ws_size - 8192 : 0;
  int C = (int)(usable / perB);
  if (C > B) C = B;
  if (C < 1) C = 1;

  char* p = (char*)d_ws;
  auto alloc = [&](size_t bytes) {
    char* r = p; p += (bytes + 255) & ~(size_t)255; return r;
  };
  unsigned short* simq = (unsigned short*)alloc((size_t)C * QL * D * 2);  // later P
  unsigned short* simk = (unsigned short*)alloc((size_t)C * SL * D * 2);
  unsigned short* ctxT = (unsigned short*)alloc((size_t)C * D * SL * 2);
  float* Sbuf = (float*)alloc((size_t)C * QL * SL * 4);                   // later wc
  float* rn   = (float*)alloc((size_t)C * SL * 4);

  for (int b0 = 0; b0 < B; b0 += C) {
    const int Cc = (B - b0) < C ? (B - b0) : C;
    hipMemsetAsync(rn, 0, (size_t)Cc * SL * 4, stream);
    // projections: sim_q = query Wq^T + bq ; sim_k = ctx Wk^T + bk  (bf16 out)
    gemm_bt<0><<<dim3(Cc * 4 * NTILES), 256, 0, stream>>>(
        query + (size_t)b0 * QL * D, Wq, bq, simq, nullptr, Cc * 4, 0, 0, 0, 0);
    gemm_bt<0><<<dim3(Cc * 8 * NTILES), 256, 0, stream>>>(
        context + (size_t)b0 * SL * D, Wk, bk, simk, nullptr, Cc * 8, 0, 0, 0, 0);
    transpose_ctx_k<<<dim3(32, 32, Cc), 256, 0, stream>>>(
        context + (size_t)b0 * SL * D, ctxT);
    // S^T[q][s] = leaky(simq . simk), rnorm2[s] += sum_q leaky^2
    gemm_bt<1><<<dim3(Cc * 4 * NTILES), 256, 0, stream>>>(
        simq, simk, nullptr, Sbuf, rn, 4,
        (long long)QL * D, (long long)SL * D, (long long)QL * SL, (long long)SL);
    softmax_k<<<Cc * QL, 256, 0, stream>>>(Sbuf, rn, smooth, simq /* P */);
    // wc = P @ ctxT^T  (contraction over s)
    gemm_bt<2><<<dim3(Cc * 4 * NTILES), 256, 0, stream>>>(
        simq /* P */, ctxT, nullptr, Sbuf /* wc */, nullptr, 4,
        (long long)QL * SL, (long long)D * SL, (long long)QL * D, 0);
    l2norm_k<<<Cc * QL, 256, 0, stream>>>(Sbuf, out + (size_t)b0 * QL * D);
  }
}